// Round 1
// baseline (598.674 us; speedup 1.0000x reference)
//
#include <hip/hip_runtime.h>
#include <stdint.h>

// BaseOpenSetClassifier: per-pixel sq-euclid distance to K templates + min/argmin.
// B=16, N=16384, D=64, K=64, thresholds {0.5, 1.0}.
//
// R8 = lane-per-template redesign ("scheme A").
// EVIDENCE (R6/R7): kernel was issue/latency-bound, not BW-bound (R6: VALUBusy
// 59%, hbm 1.2 TB/s @168us; R7 < 159us but still ~2x off the 51us / 6.3 TB/s
// stream floor for the fixed 320 MB of traffic). Root cause: per-8k-chunk
// serial 3-deep ds_swizzle reduction chains + cndmask b-folds in the hot loop.
// Changes:
//  - wave = 1 pixel, lane = k (64 templates). Template row resident in regs
//    (one 32-float d-half at a time -> 16 v2f). x rows are wave-uniform
//    broadcast float4 loads (1 line-request per load). Hot loop is PURE
//    per-lane pk_sub/pk_fma streaming: 1 packed instr/element, 0 shuffles,
//    0 horizontal ops, 0 compares.
//  - min/argmin ONCE in the epilogue: per b, 6-step shfl_xor min + ballot
//    (d == m) + ffsll -> first-index tie semantics == jnp.argmin. All 16 b
//    reductions are independent -> compiler interleaves (no exposed DS chain).
//  - acc[16] is v2f (even/odd element sums); d = acc.x+acc.y at the end.
//  - __launch_bounds__(256,2): caps VGPR ~128 (R7 note: arg 4 forced <=64 +
//    spills; arg 1 let regs float). Target ~115 live (32 acc + 32 t + window)
//    -> 4 waves/SIMD.
//  - XCD swizzle: block g's 4 pixels = ((g&7)<<11) | ((g>>3)<<2) | wave, so
//    each XCD owns a contiguous 2048-pixel range -> keeps R7's dense-write-line
//    fix (out writes are 4B @ 64KB stride; neighbors-in-line = neighbor pixels
//    on the same XCD).

#define BB 16
#define NN 16384
#define DD 64
#define KK 64

typedef float v2f __attribute__((ext_vector_type(2)));

__global__ __launch_bounds__(256, 2)
void openset_kernel(const float* __restrict__ x,     // [B,N,D]
                    const float* __restrict__ tmpl,  // [K,N,D]
                    const int*   __restrict__ tcls,  // [K]
                    float*       __restrict__ out) { // [2*B*N | B*N | B*N]
    const int lane = threadIdx.x & 63;
    const int wv   = threadIdx.x >> 6;
    // 4096 blocks x 4 waves; XCD i (= blk&7) owns pixels [i*2048, (i+1)*2048).
    const int p = (int)(((blockIdx.x & 7) << 11) | ((blockIdx.x >> 3) << 2)) | wv;

    // lane = template index k. Row stride N*D = 2^20 floats (4 MiB).
    const float* tb = tmpl + ((size_t)lane << 20) + (size_t)p * DD;
    const float* xb = x + (size_t)p * DD;

    v2f acc[BB];
#pragma unroll
    for (int b = 0; b < BB; ++b) acc[b] = (v2f){0.f, 0.f};

    // Two d-halves of 32 floats: template half resident (16 v2f), then sweep
    // all 16 batch rows against it. Per (b,j): 2 pk_sub + 2 pk_fma for 4
    // elements = the packed-fp32 ideal.
#pragma unroll
    for (int h = 0; h < 2; ++h) {
        v2f t[16];
#pragma unroll
        for (int j = 0; j < 8; ++j) {
            float4 tv = *(const float4*)(tb + 32 * h + 4 * j);
            t[2 * j]     = (v2f){tv.x, tv.y};
            t[2 * j + 1] = (v2f){tv.z, tv.w};
        }
#pragma unroll
        for (int b = 0; b < BB; ++b) {
            const float* xr = xb + ((size_t)b << 20) + 32 * h;
            v2f a0 = (v2f){0.f, 0.f};
            v2f a1 = (v2f){0.f, 0.f};
#pragma unroll
            for (int j = 0; j < 8; ++j) {
                float4 xv = *(const float4*)(xr + 4 * j);  // wave-uniform bcast
                v2f d0 = (v2f){xv.x, xv.y} - t[2 * j];
                v2f d1 = (v2f){xv.z, xv.w} - t[2 * j + 1];
                a0 += d0 * d0;   // pk_fma chain (depth 8)
                a1 += d1 * d1;   // independent chain -> ILP
            }
            acc[b] += a0 + a1;
        }
    }

    // Epilogue: per-b min over the 64 lanes (= 64 k's), argmin via ballot.
    // All 16 b's independent -> shfl latency overlapped by the compiler.
    float bestd = 0.f;
    int   bestk = 0;
#pragma unroll
    for (int b = 0; b < BB; ++b) {
        const float dme = acc[b].x + acc[b].y;  // full 64-d distance, lane = k
        float m = dme;
#pragma unroll
        for (int i = 1; i < 64; i <<= 1)
            m = fminf(m, __shfl_xor(m, i));      // m = global min, all lanes
        const unsigned long long tie = __ballot(dme == m);
        const int ks = __ffsll(tie) - 1;         // first (smallest) k == argmin
        if (lane == b) { bestd = m; bestk = ks; }
    }

    // Lane b (< 16) writes pixel p's 4 outputs for batch row b.
    if (lane < BB) {
        const size_t BN = (size_t)BB * NN;
        const size_t o  = (size_t)lane * NN + p;
        out[o]          = (bestd <= 0.5f) ? 1.0f : 0.0f;  // masks[0] @0.5
        out[BN + o]     = (bestd <= 1.0f) ? 1.0f : 0.0f;  // masks[1] @1.0
        out[2 * BN + o] = bestd;                          // min_dists
        out[3 * BN + o] = (float)tcls[bestk];             // pred_classes
    }
}

extern "C" void kernel_launch(void* const* d_in, const int* in_sizes, int n_in,
                              void* d_out, int out_size, void* d_ws, size_t ws_size,
                              hipStream_t stream) {
    const float* x    = (const float*)d_in[0];   // frame_embeddings [16,16384,64]
    const float* tmpl = (const float*)d_in[1];   // templates       [64,16384,64]
    const int*   tcls = (const int*)d_in[2];     // template_classes [64]
    float* out = (float*)d_out;

    dim3 grid(NN / 4);    // 4096 blocks: 4 waves = 4 pixels each
    dim3 block(256);
    openset_kernel<<<grid, block, 0, stream>>>(x, tmpl, tcls, out);
}

// Round 2
// 493.021 us; speedup vs baseline: 1.2143x; 1.2143x over previous
//
#include <hip/hip_runtime.h>
#include <stdint.h>

// BaseOpenSetClassifier: per-pixel sq-euclid distance to K templates + min/argmin.
// B=16, N=16384, D=64, K=64, thresholds {0.5, 1.0}.
//
// R9 = R8's lane-per-template compute + LDS-transposed coalesced loads.
// EVIDENCE (R8): 328us, hbm 511 GB/s (6.4%), VALUBusy 12% -> latency-bound on
// a 64-way scattered gather (lane=k direct loads hit 64 lines 4MiB apart per
// instr). Fix: templates for 4 CONSECUTIVE pixels are contiguous (1 KB per k),
// so a block (4 waves = pixels p0..p0+3) stages t[k, p0:p0+4, :] for all k
// into 64 KB LDS with perfectly-coalesced 1KB wave-loads, then computes with
// the R8 lane=k structure (zero in-loop shuffles; verified epilogue).
//  - LDS slot for chunk k, within-chunk float4 i (= pp*16+j): k*64 + (i^(k&7)).
//    Guide G4 XOR swizzle: write side (contiguous, lanes permuted in octets)
//    and read side (1KB-strided rows, octet covers 8 distinct bank-groups)
//    both conflict-free.
//  - x side: wave-uniform float4 broadcast loads (1 line/request; fine in R8).
//  - epilogue: R8's verified shfl_xor min + ballot/ffs argmin (first-index
//    ties == jnp.argmin), then LDS-transposed store: wave wv writes plane wv
//    as 64 lanes x (b,pp) -> 16x16B segments instead of 16x4B scatter.
//  - 2 blocks/CU (64.5 KB LDS): block n+1 stages while block n computes;
//    HBM budget/block ~8.2k cyc >> compute ~2.4k cyc -> BW-bound by design.
//  - __launch_bounds__(256,2): VGPR cap 256 (LDS limits occupancy anyway).

#define BB 16
#define NN 16384
#define DD 64
#define KK 64

typedef float v2f __attribute__((ext_vector_type(2)));

__global__ __launch_bounds__(256, 2)
void openset_kernel(const float* __restrict__ x,     // [B,N,D]
                    const float* __restrict__ tmpl,  // [K,N,D]
                    const int*   __restrict__ tcls,  // [K]
                    float*       __restrict__ out) { // [2*B*N | B*N | B*N]
    __shared__ float4 sbuf[KK * 64];   // 64 KB template tile, swizzled
    __shared__ float2 sc[64];          // epilogue scratch [pp][b]

    const int lane = threadIdx.x & 63;
    const int wv   = threadIdx.x >> 6;
    // XCD swizzle: XCD i (= blk&7) owns pixels [i*2048, (i+1)*2048), p0 step 4.
    const int p0 = (int)(((blockIdx.x & 7) << 11) | ((blockIdx.x >> 3) << 2));
    const int p  = p0 + wv;            // this wave's pixel

    // ---- Stage templates: wave wv stages chunks k = wv*16 .. wv*16+15.
    // Chunk k = t[k, p0:p0+4, 0:64], 1 KB contiguous -> one coalesced
    // wave-load; lane i holds float4 (pp = i>>4, j = i&15).
#pragma unroll
    for (int c = 0; c < 16; ++c) {
        const int k = wv * 16 + c;
        const float4* src =
            (const float4*)(tmpl + ((size_t)k << 20)) + (size_t)p0 * 16;
        sbuf[k * 64 + (lane ^ (k & 7))] = src[lane];
    }
    __syncthreads();

    // ---- Own template row (lane = k) for pixel p into regs: i = wv*16 + j.
    float4 t4[16];
#pragma unroll
    for (int j = 0; j < 16; ++j)
        t4[j] = sbuf[lane * 64 + ((wv * 16 + j) ^ (lane & 7))];

    // ---- Hot loop: pure per-lane packed math, zero cross-lane ops.
    v2f acc[BB];
#pragma unroll
    for (int b = 0; b < BB; ++b) {
        const float* xr = x + ((size_t)b << 20) + (size_t)p * DD;
        v2f a0 = (v2f){0.f, 0.f};
        v2f a1 = (v2f){0.f, 0.f};
#pragma unroll
        for (int j = 0; j < 16; ++j) {
            float4 xv = *(const float4*)(xr + 4 * j);   // wave-uniform bcast
            float4 tv = t4[j];
            v2f d0 = (v2f){xv.x - tv.x, xv.y - tv.y};
            v2f d1 = (v2f){xv.z - tv.z, xv.w - tv.w};
            a0 += d0 * d0;      // pk_fma chain, two independent chains for ILP
            a1 += d1 * d1;
        }
        acc[b] = a0 + a1;
    }

    // ---- Epilogue (R8-verified): per-b min over 64 lanes (= 64 k's),
    // argmin via ballot+ffs -> first-index tie semantics == jnp.argmin.
    float bestd = 0.f;
    int   bestk = 0;
#pragma unroll
    for (int b = 0; b < BB; ++b) {
        const float dme = acc[b].x + acc[b].y;
        float m = dme;
#pragma unroll
        for (int i = 1; i < 64; i <<= 1)
            m = fminf(m, __shfl_xor(m, i));
        const unsigned long long tie = __ballot(dme == m);
        const int ks = __ffsll(tie) - 1;
        if (lane == b) { bestd = m; bestk = ks; }
    }
    if (lane < BB) sc[wv * 16 + lane] = make_float2(bestd, (float)tcls[bestk]);
    __syncthreads();

    // ---- Transposed store: wave wv writes plane wv for all 16 b x 4 pp.
    // lane -> (b = lane>>2, pp = lane&3): 16 contiguous 16B segments/instr.
    const int b  = lane >> 2;
    const int pp = lane & 3;
    const float2 v = sc[pp * 16 + b];
    const float o = (wv == 0) ? ((v.x <= 0.5f) ? 1.0f : 0.0f)
                  : (wv == 1) ? ((v.x <= 1.0f) ? 1.0f : 0.0f)
                  : (wv == 2) ? v.x
                              : v.y;
    out[(size_t)wv * (BB * NN) + (size_t)b * NN + p0 + pp] = o;
}

extern "C" void kernel_launch(void* const* d_in, const int* in_sizes, int n_in,
                              void* d_out, int out_size, void* d_ws, size_t ws_size,
                              hipStream_t stream) {
    const float* x    = (const float*)d_in[0];   // frame_embeddings [16,16384,64]
    const float* tmpl = (const float*)d_in[1];   // templates       [64,16384,64]
    const int*   tcls = (const int*)d_in[2];     // template_classes [64]
    float* out = (float*)d_out;

    dim3 grid(NN / 4);    // 4096 blocks: 4 waves = 4 consecutive pixels
    dim3 block(256);
    openset_kernel<<<grid, block, 0, stream>>>(x, tmpl, tcls, out);
}

// Round 3
// 410.128 us; speedup vs baseline: 1.4597x; 1.2021x over previous
//
#include <hip/hip_runtime.h>
#include <stdint.h>

// BaseOpenSetClassifier: per-pixel sq-euclid distance to K templates + min/argmin.
// B=16, N=16384, D=64, K=64, thresholds {0.5, 1.0}.
//
// R10 = both operands LDS-staged, small blocks for phase overlap.
// EVIDENCE (R9): 213us, hbm 10%, VALUBusy 20%, occ 21.5%. Template gather
// fixed, but x was 256 wave-uniform 16B loads/wave, each missing to HBM
// (~900cyc, ~7 in flight at VGPR=128, 2 waves/SIMD) -> ~30k cyc/block vs 8k
// HBM budget. LDS bank conflicts (1.08M) = t4-read octet serialization, ~1%.
// Changes:
//  - Block = 2 waves = 2 consecutive pixels. LDS: t[0:64, p0:p0+2, :] 32KB
//    (chunk k = 512B contiguous; one wave-load spans 2 chunks, lanes 0-31 /
//    32-63) + x[0:16, p0:p0+2, :] 8KB. 40KB -> 4 blocks/CU: 3 blocks compute
//    while 1 stages -> staging latency hidden (R9 had only 2 blocks/CU and
//    in-loop HBM deps).
//  - Hot-loop x reads = uniform ds_read_b128 broadcasts (no conflicts, ~120cyc
//    hideable) instead of HBM. t4 reads keep R9's verified k&7 XOR swizzle.
//  - absmax 0.0->0.5 in R9 (passed, but regression): restore R8-EXACT
//    numerics (per-half fresh a0/a1 chains, acc[b] += a0+a1) and R8's direct
//    lane<16 store, so only the load path differs from the absmax-0.0 kernel.
//  - BW-bound by design: 8192 blocks x 40KB = 320MB compulsory -> ~60us floor
//    (less if L3 absorbs re-reads as R9's FETCH=164MB indicates).

#define BB 16
#define NN 16384
#define DD 64
#define KK 64

typedef float v2f __attribute__((ext_vector_type(2)));

__global__ __launch_bounds__(128, 2)
void openset_kernel(const float* __restrict__ x,     // [B,N,D]
                    const float* __restrict__ tmpl,  // [K,N,D]
                    const int*   __restrict__ tcls,  // [K]
                    float*       __restrict__ out) { // [2*B*N | B*N | B*N]
    __shared__ float4 st[KK * 32];   // 32 KB: chunk k = t[k, p0:p0+2, 0:64]
    __shared__ float4 sx[BB * 32];   // 8 KB : row  b = x[b, p0:p0+2, 0:64]

    const int lane = threadIdx.x & 63;
    const int wv   = threadIdx.x >> 6;          // 0..1, wave = pixel
    // XCD swizzle: XCD i (= blk&7) owns pixels [i*2048, (i+1)*2048), step 2.
    const int p0   = (int)(((blockIdx.x & 7) << 11) | ((blockIdx.x >> 3) << 1));
    const int p    = p0 + wv;

    const int half = lane >> 5;                 // which chunk of the pair
    const int i32  = lane & 31;                 // float4 index within 512B

    // ---- Stage templates: 16 wave-loads/wave, each covers chunks 2c,2c+1.
    // Chunk k = t[k, p0:p0+2, :] (512B contiguous, 512B-aligned since p0 even).
    // Swizzled slot i^(k&7) (flips low 3 bits of j only -> stays in chunk).
#pragma unroll
    for (int c = 0; c < 16; ++c) {
        const int k = (wv * 16 + c) * 2 + half;
        const float4* src =
            (const float4*)(tmpl + ((size_t)k << 20)) + (size_t)p0 * 16;
        st[k * 32 + (i32 ^ (k & 7))] = src[i32];
    }
    // ---- Stage x: 4 wave-loads/wave, each covers rows 2c,2c+1. Linear.
#pragma unroll
    for (int c = 0; c < 4; ++c) {
        const int b = (wv * 4 + c) * 2 + half;
        const float4* src =
            (const float4*)(x + ((size_t)b << 20)) + (size_t)p0 * 16;
        sx[b * 32 + i32] = src[i32];
    }
    __syncthreads();

    // ---- Own template row (lane = k) for pixel p: 16 float4 from LDS.
    float4 t4[16];
#pragma unroll
    for (int j = 0; j < 16; ++j)
        t4[j] = st[lane * 32 + ((wv * 16 + j) ^ (lane & 7))];

    // ---- Hot loop: R8-EXACT accumulation order (absmax-0.0 provenance).
    v2f acc[BB];
#pragma unroll
    for (int b = 0; b < BB; ++b) acc[b] = (v2f){0.f, 0.f};

#pragma unroll
    for (int h = 0; h < 2; ++h) {
#pragma unroll
        for (int b = 0; b < BB; ++b) {
            v2f a0 = (v2f){0.f, 0.f};
            v2f a1 = (v2f){0.f, 0.f};
#pragma unroll
            for (int j = 0; j < 8; ++j) {
                float4 xv = sx[b * 32 + wv * 16 + h * 8 + j];  // LDS bcast
                float4 tv = t4[h * 8 + j];
                v2f d0 = (v2f){xv.x - tv.x, xv.y - tv.y};
                v2f d1 = (v2f){xv.z - tv.z, xv.w - tv.w};
                a0 += d0 * d0;      // pk_fma chains, 2-way ILP
                a1 += d1 * d1;
            }
            acc[b] += a0 + a1;
        }
    }

    // ---- Epilogue (R8-verified): per-b min over 64 lanes (= 64 k's),
    // argmin via ballot+ffs -> first-index tie semantics == jnp.argmin.
    float bestd = 0.f;
    int   bestk = 0;
#pragma unroll
    for (int b = 0; b < BB; ++b) {
        const float dme = acc[b].x + acc[b].y;
        float m = dme;
#pragma unroll
        for (int i = 1; i < 64; i <<= 1)
            m = fminf(m, __shfl_xor(m, i));
        const unsigned long long tie = __ballot(dme == m);
        const int ks = __ffsll(tie) - 1;
        if (lane == b) { bestd = m; bestk = ks; }
    }

    // ---- R8's direct store: lane b (<16) writes pixel p's 4 outputs.
    if (lane < BB) {
        const size_t BN = (size_t)BB * NN;
        const size_t o  = (size_t)lane * NN + p;
        out[o]          = (bestd <= 0.5f) ? 1.0f : 0.0f;  // masks[0] @0.5
        out[BN + o]     = (bestd <= 1.0f) ? 1.0f : 0.0f;  // masks[1] @1.0
        out[2 * BN + o] = bestd;                          // min_dists
        out[3 * BN + o] = (float)tcls[bestk];             // pred_classes
    }
}

extern "C" void kernel_launch(void* const* d_in, const int* in_sizes, int n_in,
                              void* d_out, int out_size, void* d_ws, size_t ws_size,
                              hipStream_t stream) {
    const float* x    = (const float*)d_in[0];   // frame_embeddings [16,16384,64]
    const float* tmpl = (const float*)d_in[1];   // templates       [64,16384,64]
    const int*   tcls = (const int*)d_in[2];     // template_classes [64]
    float* out = (float*)d_out;

    dim3 grid(NN / 2);    // 8192 blocks: 2 waves = 2 consecutive pixels
    dim3 block(128);
    openset_kernel<<<grid, block, 0, stream>>>(x, tmpl, tcls, out);
}

// Round 4
// 400.375 us; speedup vs baseline: 1.4953x; 1.0244x over previous
//
#include <hip/hip_runtime.h>
#include <stdint.h>

// BaseOpenSetClassifier: per-pixel sq-euclid distance to K templates + min/argmin.
// B=16, N=16384, D=64, K=64, thresholds {0.5, 1.0}.
//
// R11 = R10's tile, 4x the waves sharing it (occupancy fix).
// EVIDENCE (R10): 164us, hbm 13%, VALUBusy 25%, occ 20%. No pipe busy ->
// latency-bound; 40KB/2-wave blocks capped residency at 8 waves/CU, so the
// stage barrier + LDS-read latency ran ~serial (12.3k cyc/block-round vs 4k
// HBM budget). Bank conflicts 1.05M cyc = noise. absmax 0.0 restored.
// Changes:
//  - Block = 8 waves (512 thr), SAME 2-pixel 40KB tile -> 4 WGs/CU = 32
//    waves/CU (100% cap). Wave w: pixel pp = w&1, b-quarter q = w>>1 (4 b's).
//  - t row NOT cached in regs: tv read once per (h,j) (16 strided 1KB reads
//    per wave, same count as R10) and reused across the wave's 4 b's ->
//    ~55 VGPR. __launch_bounds__(512,6): VGPR cap 80, >=3 WGs/CU by VGPR,
//    4 by LDS. (NOT (512,8): would force 64 and risk spills -- R7 lesson.)
//  - Accumulation stays R8-EXACT per b: fresh a0/a1 chains per (h,b), 8 j
//    steps, acc[b] += a0+a1 (absmax-0.0 provenance), just with j outer /
//    b inner and per-b a0[4]/a1[4] register arrays.
//  - Staging split 8 ways: 4 t wave-loads + 1 x wave-load per wave (512B
//    contiguous chunk per half-wave; p0 even -> 512B aligned).
//  - Per-CU budget: HBM 1.25MB = 53us (binding) >> LDS 19us, VALU 20us.

#define BB 16
#define NN 16384
#define DD 64
#define KK 64

typedef float v2f __attribute__((ext_vector_type(2)));

__global__ __launch_bounds__(512, 6)
void openset_kernel(const float* __restrict__ x,     // [B,N,D]
                    const float* __restrict__ tmpl,  // [K,N,D]
                    const int*   __restrict__ tcls,  // [K]
                    float*       __restrict__ out) { // [2*B*N | B*N | B*N]
    __shared__ float4 st[KK * 32];   // 32 KB: chunk k = t[k, p0:p0+2, 0:64]
    __shared__ float4 sx[BB * 32];   // 8 KB : row  b = x[b, p0:p0+2, 0:64]

    const int lane = threadIdx.x & 63;
    const int wv   = threadIdx.x >> 6;          // 0..7
    const int pp   = wv & 1;                    // wave's pixel in the pair
    const int q    = wv >> 1;                   // wave's b-quarter (4 b's)
    // XCD swizzle: XCD i (= blk&7) owns pixels [i*2048, (i+1)*2048), step 2.
    const int p0   = (int)(((blockIdx.x & 7) << 11) | ((blockIdx.x >> 3) << 1));

    const int half = lane >> 5;                 // which chunk of a pair
    const int i32  = lane & 31;                 // float4 index within 512B

    // ---- Stage templates: wave w covers chunks k in [8w, 8w+8), 4 loads.
    // Chunk k = t[k, p0:p0+2, :] (512B contiguous, 512B-aligned, p0 even).
    // Swizzled slot i^(k&7) flips low 3 bits of j only -> stays in chunk.
#pragma unroll
    for (int c = 0; c < 4; ++c) {
        const int k = (wv * 4 + c) * 2 + half;
        const float4* src =
            (const float4*)(tmpl + ((size_t)k << 20)) + (size_t)p0 * 16;
        st[k * 32 + (i32 ^ (k & 7))] = src[i32];
    }
    // ---- Stage x: wave w covers rows b = 2w, 2w+1 in one load. Linear.
    {
        const int b = wv * 2 + half;
        const float4* src =
            (const float4*)(x + ((size_t)b << 20)) + (size_t)p0 * 16;
        sx[b * 32 + i32] = src[i32];
    }
    __syncthreads();

    // ---- Hot loop: lane = k. tv read once per (h,j), reused over 4 b's.
    // R8-EXACT accumulation: per b, fresh a0/a1 per h, 8 j-steps, then
    // acc[b] += a0 + a1.
    v2f acc[4];
#pragma unroll
    for (int i = 0; i < 4; ++i) acc[i] = (v2f){0.f, 0.f};

#pragma unroll
    for (int h = 0; h < 2; ++h) {
        v2f a0[4], a1[4];
#pragma unroll
        for (int i = 0; i < 4; ++i) { a0[i] = (v2f){0.f, 0.f}; a1[i] = (v2f){0.f, 0.f}; }
#pragma unroll
        for (int j = 0; j < 8; ++j) {
            const int e = pp * 16 + h * 8 + j;
            const float4 tv = st[lane * 32 + (e ^ (lane & 7))];   // 1KB strided
#pragma unroll
            for (int i = 0; i < 4; ++i) {
                const float4 xv = sx[(q * 4 + i) * 32 + e];       // uniform bcast
                v2f d0 = (v2f){xv.x - tv.x, xv.y - tv.y};
                v2f d1 = (v2f){xv.z - tv.z, xv.w - tv.w};
                a0[i] += d0 * d0;      // pk_fma chains, 2-way ILP per b
                a1[i] += d1 * d1;
            }
        }
#pragma unroll
        for (int i = 0; i < 4; ++i) acc[i] += a0[i] + a1[i];
    }

    // ---- Epilogue (R8-verified): per-b min over 64 lanes (= 64 k's),
    // argmin via ballot+ffs -> first-index tie semantics == jnp.argmin.
    float bestd = 0.f;
    int   bestk = 0;
#pragma unroll
    for (int i = 0; i < 4; ++i) {
        const float dme = acc[i].x + acc[i].y;
        float m = dme;
#pragma unroll
        for (int s = 1; s < 64; s <<= 1)
            m = fminf(m, __shfl_xor(m, s));
        const unsigned long long tie = __ballot(dme == m);
        const int ks = __ffsll(tie) - 1;
        if (lane == i) { bestd = m; bestk = ks; }
    }

    // ---- Store: lane i (<4) holds (bestd,bestk) for b = q*4 + i, pixel p.
    if (lane < 4) {
        const int b = q * 4 + lane;
        const size_t BN = (size_t)BB * NN;
        const size_t o  = (size_t)b * NN + (p0 + pp);
        out[o]          = (bestd <= 0.5f) ? 1.0f : 0.0f;  // masks[0] @0.5
        out[BN + o]     = (bestd <= 1.0f) ? 1.0f : 0.0f;  // masks[1] @1.0
        out[2 * BN + o] = bestd;                          // min_dists
        out[3 * BN + o] = (float)tcls[bestk];             // pred_classes
    }
}

extern "C" void kernel_launch(void* const* d_in, const int* in_sizes, int n_in,
                              void* d_out, int out_size, void* d_ws, size_t ws_size,
                              hipStream_t stream) {
    const float* x    = (const float*)d_in[0];   // frame_embeddings [16,16384,64]
    const float* tmpl = (const float*)d_in[1];   // templates       [64,16384,64]
    const int*   tcls = (const int*)d_in[2];     // template_classes [64]
    float* out = (float*)d_out;

    dim3 grid(NN / 2);    // 8192 blocks: 8 waves, 2 consecutive pixels
    dim3 block(512);
    openset_kernel<<<grid, block, 0, stream>>>(x, tmpl, tcls, out);
}